// Round 1
// baseline (104.736 us; speedup 1.0000x reference)
//
#include <hip/hip_runtime.h>
#include <math.h>

#define BB 4
#define NN 256
#define DD 128
#define CDIM 3

// ws layout: H1a [B*N*D] floats, then H1b [B*N*D] floats (total 1 MB).

__global__ __launch_bounds__(256) void h1_kernel(
    const float* __restrict__ emb,   // B*N*D
    const float* __restrict__ mW1,   // 2D*D row-major
    const float* __restrict__ mb1,   // D
    float* __restrict__ H1a,
    float* __restrict__ H1b)
{
    // 256 blocks, 256 threads. Each block: 4 rows. e = tid&127, dh = tid>>7 splits d-range.
    const int tid  = threadIdx.x;
    const int e    = tid & 127;
    const int dh   = tid >> 7;          // 0/1
    const int row0 = blockIdx.x * 4;    // global row = b*N + i

    __shared__ float embS[4][DD];
    __shared__ float pA[2][4][DD];
    __shared__ float pB[2][4][DD];

    for (int k = tid; k < 4 * DD; k += 256)
        embS[k >> 7][k & 127] = emb[row0 * DD + k];
    __syncthreads();

    float accA[4] = {0.f, 0.f, 0.f, 0.f};
    float accB[4] = {0.f, 0.f, 0.f, 0.f};
    const int d0 = dh * 64;
    #pragma unroll 8
    for (int dd = 0; dd < 64; ++dd) {
        const int d = d0 + dd;
        const float wa = mW1[d * DD + e];
        const float wb = mW1[(DD + d) * DD + e];
        #pragma unroll
        for (int r = 0; r < 4; ++r) {
            accA[r] = fmaf(embS[r][d], wa, accA[r]);
            accB[r] = fmaf(embS[r][d], wb, accB[r]);
        }
    }
    #pragma unroll
    for (int r = 0; r < 4; ++r) {
        pA[dh][r][e] = accA[r];
        pB[dh][r][e] = accB[r];
    }
    __syncthreads();

    if (dh == 0) {
        const float bias = mb1[e];
        #pragma unroll
        for (int r = 0; r < 4; ++r)
            H1a[(row0 + r) * DD + e] = pA[0][r][e] + pA[1][r][e] + bias;
    } else {
        #pragma unroll
        for (int r = 0; r < 4; ++r)
            H1b[(row0 + r) * DD + e] = pB[0][r][e] + pB[1][r][e];
    }
}

__global__ __launch_bounds__(512) void gnn_kernel(
    const float* __restrict__ emb,
    const float* __restrict__ coords,  // B*N*3
    const float* __restrict__ mW2, const float* __restrict__ mb2,
    const float* __restrict__ uW1, const float* __restrict__ ub1,
    const float* __restrict__ uW2, const float* __restrict__ ub2,
    const float* __restrict__ H1a, const float* __restrict__ H1b,
    float* __restrict__ out)
{
    const int tid  = threadIdx.x;
    const int e    = tid & 127;
    const int r    = tid >> 7;           // 0..3: row within block
    const int row0 = blockIdx.x * 4;     // 256 blocks; rows row0..row0+3, same b
    const int b    = row0 >> 8;
    const int i    = (row0 & 255) + r;
    const int grow = row0 + r;           // = b*256 + i

    __shared__ float cS[NN][CDIM];       // 3 KB
    __shared__ float A_s[4][NN];         // 4 KB
    __shared__ float R_s[4][DD];         // 2 KB
    __shared__ float U_s[4][DD + 4];     // upd_in (128 agg + 3 coords)
    __shared__ float h_s[4][DD];         // 2 KB

    for (int k = tid; k < NN * CDIM; k += 512)
        (&cS[0][0])[k] = coords[b * NN * CDIM + k];
    __syncthreads();

    // A rows for the 4 i's handled by this block (1024 values / 512 threads)
    for (int idx = tid; idx < 4 * NN; idx += 512) {
        const int rr = idx >> 8;
        const int j  = idx & 255;
        const int ii = (row0 & 255) + rr;
        const float dx = cS[j][0] - cS[ii][0];
        const float dy = cS[j][1] - cS[ii][1];
        const float dz = cS[j][2] - cS[ii][2];
        A_s[rr][j] = __expf(-0.5f * (dx * dx + dy * dy + dz * dz));
    }
    __syncthreads();

    // Dominant loop: R[i,e] = sum_j A[i,j] * relu(h1a[i,e] + h1b[j,e]); sA = sum_j A[i,j]
    const float h1a_ie = H1a[grow * DD + e];
    const float* __restrict__ h1bp = H1b + b * NN * DD + e;
    float acc = 0.f, sA = 0.f;
    #pragma unroll 8
    for (int j = 0; j < NN; ++j) {
        const float a = A_s[r][j];
        sA += a;
        const float v = h1bp[j * DD];
        acc = fmaf(a, fmaxf(h1a_ie + v, 0.f), acc);
    }
    R_s[r][e] = acc;
    __syncthreads();

    // agg = R @ mW2 + sA * mb2
    float agg = sA * mb2[e];
    #pragma unroll 8
    for (int d = 0; d < DD; ++d)
        agg = fmaf(R_s[r][d], mW2[d * DD + e], agg);
    U_s[r][e] = agg;
    if (e < CDIM) U_s[r][DD + e] = cS[i][e];
    __syncthreads();

    // hid = relu(upd_in @ uW1 + ub1)
    float h = ub1[e];
    #pragma unroll 8
    for (int d = 0; d < DD + CDIM; ++d)
        h = fmaf(U_s[r][d], uW1[d * DD + e], h);
    h = fmaxf(h, 0.f);
    h_s[r][e] = h;
    __syncthreads();

    // delta = hid @ uW2 + ub2 ; out = emb + delta
    float delta = ub2[e];
    #pragma unroll 8
    for (int d = 0; d < DD; ++d)
        delta = fmaf(h_s[r][d], uW2[d * DD + e], delta);
    out[grow * DD + e] = emb[grow * DD + e] + delta;
}

extern "C" void kernel_launch(void* const* d_in, const int* in_sizes, int n_in,
                              void* d_out, int out_size, void* d_ws, size_t ws_size,
                              hipStream_t stream) {
    const float* emb    = (const float*)d_in[0];
    const float* coords = (const float*)d_in[1];
    const float* mW1    = (const float*)d_in[2];
    const float* mb1    = (const float*)d_in[3];
    const float* mW2    = (const float*)d_in[4];
    const float* mb2    = (const float*)d_in[5];
    const float* uW1    = (const float*)d_in[6];
    const float* ub1    = (const float*)d_in[7];
    const float* uW2    = (const float*)d_in[8];
    const float* ub2    = (const float*)d_in[9];
    float* out = (float*)d_out;

    float* H1a = (float*)d_ws;
    float* H1b = H1a + BB * NN * DD;

    h1_kernel<<<dim3(BB * NN / 4), dim3(256), 0, stream>>>(emb, mW1, mb1, H1a, H1b);
    gnn_kernel<<<dim3(BB * NN / 4), dim3(512), 0, stream>>>(
        emb, coords, mW2, mb2, uW1, ub1, uW2, ub2, H1a, H1b, out);
}

// Round 3
// 102.227 us; speedup vs baseline: 1.0245x; 1.0245x over previous
//
#include <hip/hip_runtime.h>
#include <math.h>

#define BB 4
#define NN 256
#define DD 128
#define CDIM 3

// relu-weighted fma: acc += a * relu(p + v), componentwise
#define FMA4R(acc, a, p, v)                              \
  acc.x = fmaf(a, fmaxf(p.x + v.x, 0.f), acc.x);         \
  acc.y = fmaf(a, fmaxf(p.y + v.y, 0.f), acc.y);         \
  acc.z = fmaf(a, fmaxf(p.z + v.z, 0.f), acc.z);         \
  acc.w = fmaf(a, fmaxf(p.w + v.w, 0.f), acc.w);

// plain fma: acc += s * v
#define FMA4(acc, s, v)                                  \
  acc.x = fmaf(s, v.x, acc.x);                           \
  acc.y = fmaf(s, v.y, acc.y);                           \
  acc.z = fmaf(s, v.z, acc.z);                           \
  acc.w = fmaf(s, v.w, acc.w);

// ---------------------------------------------------------------------------
// h1_kernel: H1a = emb@W1a + mb1 ; H1b = emb@W1b
// 256 blocks x 512 threads, 4 rows/block. Full mW1 (128 KB) staged in LDS.
// ---------------------------------------------------------------------------
__global__ __launch_bounds__(512) void h1_kernel(
    const float* __restrict__ emb,   // [1024][128]
    const float* __restrict__ mW1,   // [256][128]
    const float* __restrict__ mb1,   // [128]
    float* __restrict__ H1a,
    float* __restrict__ H1b)
{
    const int tid  = threadIdx.x;
    const int row0 = blockIdx.x * 4;

    __shared__ float4 WL[8192];          // 128 KB: mW1 as [256 rows][32 quads]
    __shared__ float  embS[4 * DD];      // 2 KB
    __shared__ float4 red4[4][4][64];    // 16 KB: [dq][row][oq]

    // issue all staging loads first (16 dwordx4 in flight per thread)
    const float4* __restrict__ W4 = (const float4*)mW1;
    float4 st[16];
    #pragma unroll
    for (int k = 0; k < 16; ++k) st[k] = W4[k * 512 + tid];
    const float ev = emb[(size_t)row0 * DD + tid];

    #pragma unroll
    for (int k = 0; k < 16; ++k) WL[k * 512 + tid] = st[k];
    embS[tid] = ev;
    __syncthreads();

    // thread = (dq 0..3, rp 0..1, oq 0..63); 2 rows per thread, 32 d each
    const int oq = tid & 63;
    const int rp = (tid >> 6) & 1;
    const int dq = tid >> 7;
    const int r0 = rp * 2, r1 = r0 + 1;
    const int wq = oq & 31;
    const int wbase = (oq < 32) ? 0 : DD;   // H1a cols use W rows 0..127, H1b rows 128..255

    float4 a0 = {0.f,0.f,0.f,0.f}, a1 = {0.f,0.f,0.f,0.f};
    #pragma unroll 8
    for (int dd = 0; dd < 32; ++dd) {
        const int d = dq * 32 + dd;
        const float4 w = WL[(wbase + d) * 32 + wq];
        const float x0 = embS[r0 * DD + d];
        const float x1 = embS[r1 * DD + d];
        FMA4(a0, x0, w);
        FMA4(a1, x1, w);
    }
    red4[dq][r0][oq] = a0;
    red4[dq][r1][oq] = a1;
    __syncthreads();

    const float* __restrict__ redF = (const float*)red4;
    #pragma unroll
    for (int t = 0; t < 2; ++t) {
        const int oidx = t * 512 + tid;
        const int rr = oidx >> 8, oe = oidx & 255;
        float v = 0.f;
        #pragma unroll
        for (int q = 0; q < 4; ++q) v += redF[(q * 4 + rr) * 256 + oe];
        if (oe < DD) H1a[(size_t)(row0 + rr) * DD + oe]        = v + mb1[oe];
        else         H1b[(size_t)(row0 + rr) * DD + (oe - DD)] = v;
    }
}

// ---------------------------------------------------------------------------
// gnn_kernel: per block 4 output rows. Full H1b[b] (128 KB) staged in LDS,
// weights pipelined into the same region after the j-loop frees it.
// ---------------------------------------------------------------------------
__global__ __launch_bounds__(512) void gnn_kernel(
    const float* __restrict__ emb,
    const float* __restrict__ coords,  // [B][256][3]
    const float* __restrict__ mW2, const float* __restrict__ mb2,
    const float* __restrict__ uW1, const float* __restrict__ ub1,
    const float* __restrict__ uW2, const float* __restrict__ ub2,
    const float* __restrict__ H1a, const float* __restrict__ H1b,
    float* __restrict__ out)
{
    const int tid  = threadIdx.x;
    const int row0 = blockIdx.x * 4;
    const int b    = row0 >> 8;
    const int i0   = row0 & 255;

    __shared__ float4 HbL[8192];         // 128 KB: H1b[b] then weights
    __shared__ float  A_s[4][NN];        // 4 KB
    __shared__ float4 red4[8][4][32];    // 16 KB: [gq][row][eq]
    __shared__ float  sAred[8][4];
    __shared__ float  R_s[4][DD];        // 2 KB
    __shared__ float  U_s[4][DD + CDIM]; // ~2 KB
    __shared__ float  h_s[4][DD];        // 2 KB
    // total ~154 KB -> 1 block/CU

    const int eq = tid & 31;
    const int rp = (tid >> 5) & 1;
    const int gq = tid >> 6;             // 0..7 (j-split / d-split group)
    const int r0 = rp * 2, r1 = r0 + 1;
    const int rr = tid >> 7;             // assemble-phase row 0..3
    const int ea = tid & 127;            // assemble-phase col

    const float* __restrict__ cb = coords + (size_t)b * NN * CDIM;

    // ---- P0: coord loads, H1b staging issue, prefetches, A compute, staging write
    const int jA  = tid & 255;
    const int rA0 = tid >> 8;            // 0..1 -> rows rA0 and rA0+2
    const float cjx = cb[jA * 3], cjy = cb[jA * 3 + 1], cjz = cb[jA * 3 + 2];
    const float c0x = cb[(i0 + rA0) * 3],     c0y = cb[(i0 + rA0) * 3 + 1],     c0z = cb[(i0 + rA0) * 3 + 2];
    const float c1x = cb[(i0 + rA0 + 2) * 3], c1y = cb[(i0 + rA0 + 2) * 3 + 1], c1z = cb[(i0 + rA0 + 2) * 3 + 2];

    const float4* __restrict__ Hb4 = (const float4*)(H1b + (size_t)b * NN * DD);
    float4 st[16];
    #pragma unroll
    for (int k = 0; k < 16; ++k) st[k] = Hb4[k * 512 + tid];

    const float4 pa0 = ((const float4*)(H1a + (size_t)(row0 + r0) * DD))[eq];
    const float4 pa1 = ((const float4*)(H1a + (size_t)(row0 + r1) * DD))[eq];
    const float mb2v = mb2[ea], ub1v = ub1[ea], ub2v = ub2[ea];
    const float u1t0 = uW1[(DD + 0) * DD + ea];
    const float u1t1 = uW1[(DD + 1) * DD + ea];
    const float u1t2 = uW1[(DD + 2) * DD + ea];
    const float embv = emb[(size_t)(row0 + rr) * DD + ea];

    {
        float dx = cjx - c0x, dy = cjy - c0y, dz = cjz - c0z;
        A_s[rA0][jA]     = __expf(-0.5f * (dx * dx + dy * dy + dz * dz));
        dx = cjx - c1x; dy = cjy - c1y; dz = cjz - c1z;
        A_s[rA0 + 2][jA] = __expf(-0.5f * (dx * dx + dy * dy + dz * dz));
    }
    #pragma unroll
    for (int k = 0; k < 16; ++k) HbL[k * 512 + tid] = st[k];
    __syncthreads();

    // ---- P1: issue mW2 loads; j-loop from LDS (2 rows x 32 j per thread)
    const float4* __restrict__ W24 = (const float4*)mW2;
    float4 wst[8];
    #pragma unroll
    for (int k = 0; k < 8; ++k) wst[k] = W24[k * 512 + tid];

    float4 acc0 = {0.f,0.f,0.f,0.f}, acc1 = {0.f,0.f,0.f,0.f};
    float sA0 = 0.f, sA1 = 0.f;
    #pragma unroll 8
    for (int jj = 0; jj < 32; ++jj) {
        const int j = gq * 32 + jj;
        const float a0v = A_s[r0][j];
        const float a1v = A_s[r1][j];
        const float4 v = HbL[j * 32 + eq];
        FMA4R(acc0, a0v, pa0, v);
        FMA4R(acc1, a1v, pa1, v);
        sA0 += a0v; sA1 += a1v;
    }
    __syncthreads();   // everyone done reading H1b from LDS

    // ---- P2: issue uW1 (rows 0..127); write mW2 -> HbL[0:4096]; dump j-partials
    const float4* __restrict__ U14 = (const float4*)uW1;
    float4 u1st[8];
    #pragma unroll
    for (int k = 0; k < 8; ++k) u1st[k] = U14[k * 512 + tid];
    #pragma unroll
    for (int k = 0; k < 8; ++k) HbL[k * 512 + tid] = wst[k];
    red4[gq][r0][eq] = acc0;
    red4[gq][r1][eq] = acc1;
    if (eq == 0) { sAred[gq][r0] = sA0; sAred[gq][r1] = sA1; }
    __syncthreads();

    // ---- P3a: issue uW2; R-reduce
    const float4* __restrict__ U24 = (const float4*)uW2;
    float4 u2st[8];
    #pragma unroll
    for (int k = 0; k < 8; ++k) u2st[k] = U24[k * 512 + tid];
    const float* __restrict__ redF = (const float*)red4;
    {
        float v = 0.f;
        #pragma unroll
        for (int q = 0; q < 8; ++q) v += redF[(q * 4 + rr) * 128 + ea];
        R_s[rr][ea] = v;
    }
    __syncthreads();

    // ---- P3b: GEMV1 agg partials (mW2 in HbL first half); write uW1 -> second half
    #pragma unroll
    for (int k = 0; k < 8; ++k) HbL[4096 + k * 512 + tid] = u1st[k];
    float4 g0 = {0.f,0.f,0.f,0.f}, g1 = {0.f,0.f,0.f,0.f};
    #pragma unroll
    for (int dd = 0; dd < 16; ++dd) {
        const int d = gq * 16 + dd;
        const float u0  = R_s[r0][d];
        const float u1v = R_s[r1][d];
        const float4 w = HbL[d * 32 + eq];
        FMA4(g0, u0, w);
        FMA4(g1, u1v, w);
    }
    red4[gq][r0][eq] = g0;
    red4[gq][r1][eq] = g1;
    __syncthreads();

    // ---- P4a: U-assemble (agg + sA*mb2, coords tail)
    {
        float sAt = 0.f;
        #pragma unroll
        for (int q = 0; q < 8; ++q) sAt += sAred[q][rr];
        float U = sAt * mb2v;
        #pragma unroll
        for (int q = 0; q < 8; ++q) U += redF[(q * 4 + rr) * 128 + ea];
        U_s[rr][ea] = U;
        if (ea < CDIM) U_s[rr][DD + ea] = cb[(i0 + rr) * 3 + ea];
    }
    __syncthreads();

    // ---- P4b: GEMV2 hidden partials (uW1 in HbL second half); write uW2 -> first half
    #pragma unroll
    for (int k = 0; k < 8; ++k) HbL[k * 512 + tid] = u2st[k];
    g0 = {0.f,0.f,0.f,0.f}; g1 = {0.f,0.f,0.f,0.f};
    #pragma unroll
    for (int dd = 0; dd < 16; ++dd) {
        const int d = gq * 16 + dd;
        const float u0  = U_s[r0][d];
        const float u1v = U_s[r1][d];
        const float4 w = HbL[4096 + d * 32 + eq];
        FMA4(g0, u0, w);
        FMA4(g1, u1v, w);
    }
    red4[gq][r0][eq] = g0;
    red4[gq][r1][eq] = g1;
    __syncthreads();

    // ---- P5a: h-assemble (+uW1 tail rows 128..130, bias, relu)
    {
        float h = ub1v;
        #pragma unroll
        for (int q = 0; q < 8; ++q) h += redF[(q * 4 + rr) * 128 + ea];
        h += U_s[rr][DD] * u1t0 + U_s[rr][DD + 1] * u1t1 + U_s[rr][DD + 2] * u1t2;
        h_s[rr][ea] = fmaxf(h, 0.f);
    }
    __syncthreads();

    // ---- P5b: GEMV3 delta partials (uW2 in HbL first half)
    g0 = {0.f,0.f,0.f,0.f}; g1 = {0.f,0.f,0.f,0.f};
    #pragma unroll
    for (int dd = 0; dd < 16; ++dd) {
        const int d = gq * 16 + dd;
        const float u0  = h_s[r0][d];
        const float u1v = h_s[r1][d];
        const float4 w = HbL[d * 32 + eq];
        FMA4(g0, u0, w);
        FMA4(g1, u1v, w);
    }
    red4[gq][r0][eq] = g0;
    red4[gq][r1][eq] = g1;
    __syncthreads();

    // ---- P6: final: delta reduce + residual
    {
        float delta = ub2v;
        #pragma unroll
        for (int q = 0; q < 8; ++q) delta += redF[(q * 4 + rr) * 128 + ea];
        out[(size_t)(row0 + rr) * DD + ea] = embv + delta;
    }
}

extern "C" void kernel_launch(void* const* d_in, const int* in_sizes, int n_in,
                              void* d_out, int out_size, void* d_ws, size_t ws_size,
                              hipStream_t stream) {
    const float* emb    = (const float*)d_in[0];
    const float* coords = (const float*)d_in[1];
    const float* mW1    = (const float*)d_in[2];
    const float* mb1    = (const float*)d_in[3];
    const float* mW2    = (const float*)d_in[4];
    const float* mb2    = (const float*)d_in[5];
    const float* uW1    = (const float*)d_in[6];
    const float* ub1    = (const float*)d_in[7];
    const float* uW2    = (const float*)d_in[8];
    const float* ub2    = (const float*)d_in[9];
    float* out = (float*)d_out;

    float* H1a = (float*)d_ws;
    float* H1b = H1a + BB * NN * DD;

    h1_kernel<<<dim3(BB * NN / 4), dim3(512), 0, stream>>>(emb, mW1, mb1, H1a, H1b);
    gnn_kernel<<<dim3(BB * NN / 4), dim3(512), 0, stream>>>(
        emb, coords, mW2, mb2, uW1, ub1, uW2, ub2, H1a, H1b, out);
}

// Round 4
// 82.338 us; speedup vs baseline: 1.2720x; 1.2416x over previous
//
#include <hip/hip_runtime.h>
#include <math.h>

#define NN 256
#define DD 128

typedef float4 f4;

// acc += s * v (componentwise)
#define FMA4(acc, s, v)                          \
  acc.x = fmaf(s, v.x, acc.x);                   \
  acc.y = fmaf(s, v.y, acc.y);                   \
  acc.z = fmaf(s, v.z, acc.z);                   \
  acc.w = fmaf(s, v.w, acc.w);

// acc += a * relu(p + v)
#define FMA4R(acc, a, p, v)                              \
  acc.x = fmaf(a, fmaxf(p.x + v.x, 0.f), acc.x);         \
  acc.y = fmaf(a, fmaxf(p.y + v.y, 0.f), acc.y);         \
  acc.z = fmaf(a, fmaxf(p.z + v.z, 0.f), acc.z);         \
  acc.w = fmaf(a, fmaxf(p.w + v.w, 0.f), acc.w);

#define ZERO4 {0.f, 0.f, 0.f, 0.f}

// ---------------------------------------------------------------------------
// h1_kernel: H1a = emb@W1a + mb1 ; H1b = emb@W1b
// 256 blocks x 512 threads, 4 rows/block. W streamed from global (read-once),
// emb transposed in LDS (wave-uniform b128 reads). 8-way K-split + LDS reduce.
// ---------------------------------------------------------------------------
__global__ __launch_bounds__(512, 2) void h1_kernel(
    const float* __restrict__ emb,   // [1024][128]
    const float* __restrict__ mW1,   // [256][128]
    const float* __restrict__ mb1,   // [128]
    float* __restrict__ H1a,
    float* __restrict__ H1b)
{
    const int tid  = threadIdx.x;
    const int row0 = blockIdx.x * 4;

    __shared__ f4 embT[DD];          // embT[k] = {emb[row0+0..3][k]}  (2 KB)
    __shared__ f4 red[8 * 4 * 64];   // [kh][r][cq]                    (32 KB)

    // stage emb transposed
    {
        const int r = tid >> 7, k = tid & 127;
        const float v = emb[(size_t)(row0 + r) * DD + k];
        ((float*)embT)[k * 4 + r] = v;
    }
    __syncthreads();

    const int cq    = tid & 63;              // out col quad (cols 4cq..4cq+3 of 256)
    const int kh    = tid >> 6;              // 0..7 : k in [16kh, 16kh+16)
    const int wq    = cq & 31;
    const int wrow0 = (cq < 32) ? 0 : DD;    // W1a rows 0..127 / W1b rows 128..255
    const f4* __restrict__ W4 = (const f4*)mW1;

    // preload 16 W quads (64 VGPR, all in flight)
    f4 w[16];
    #pragma unroll
    for (int t = 0; t < 16; ++t)
        w[t] = W4[(size_t)(wrow0 + kh * 16 + t) * 32 + wq];

    f4 a0 = ZERO4, a1 = ZERO4, a2 = ZERO4, a3 = ZERO4;
    #pragma unroll
    for (int t = 0; t < 16; ++t) {
        const f4 e4 = embT[kh * 16 + t];     // wave-uniform b128
        FMA4(a0, e4.x, w[t]);
        FMA4(a1, e4.y, w[t]);
        FMA4(a2, e4.z, w[t]);
        FMA4(a3, e4.w, w[t]);
    }
    red[(kh * 4 + 0) * 64 + cq] = a0;
    red[(kh * 4 + 1) * 64 + cq] = a1;
    red[(kh * 4 + 2) * 64 + cq] = a2;
    red[(kh * 4 + 3) * 64 + cq] = a3;
    __syncthreads();

    const float* __restrict__ redF = (const float*)red;
    #pragma unroll
    for (int t = 0; t < 2; ++t) {
        const int o  = t * 512 + tid;
        const int rr = o >> 8, oc = o & 255;
        float v = 0.f;
        #pragma unroll
        for (int q = 0; q < 8; ++q) v += redF[q * 1024 + rr * 256 + oc];
        if (oc < DD) H1a[(size_t)(row0 + rr) * DD + oc]        = v + mb1[oc];
        else         H1b[(size_t)(row0 + rr) * DD + (oc - DD)] = v;
    }
}

// ---------------------------------------------------------------------------
// gnn_kernel: 256 blocks x 512 threads, 4 output rows/block.
// All big streams (H1b, mW2, uW1, uW2) read once from global/L2 with explicit
// statically-indexed preload arrays; small operands transposed in LDS.
// ---------------------------------------------------------------------------
__global__ __launch_bounds__(512, 2) void gnn_kernel(
    const float* __restrict__ emb,
    const float* __restrict__ coords,  // [B][256][3]
    const float* __restrict__ mW2, const float* __restrict__ mb2,
    const float* __restrict__ uW1, const float* __restrict__ ub1,
    const float* __restrict__ uW2, const float* __restrict__ ub2,
    const float* __restrict__ H1a, const float* __restrict__ H1b,
    float* __restrict__ out)
{
    const int tid  = threadIdx.x;
    const int row0 = blockIdx.x * 4;
    const int b    = row0 >> 8;
    const int i0   = row0 & 255;

    __shared__ float cS[NN * 3];       // 3 KB
    __shared__ f4 As4[NN];             // As4[j] = A[0..3][j]     (4 KB)
    __shared__ f4 red[16 * 4 * 32];    // [part][r][eq]           (32 KB)
    __shared__ f4 R_T[DD];             // R_T[k] = R[0..3][k]     (2 KB)
    __shared__ f4 U_T[DD + 3];         // upd_in transposed       (2.1 KB)
    __shared__ f4 h_T[DD];             // hid transposed          (2 KB)
    __shared__ f4 sAs4[16];            // per-js partial sums of A rows
    __shared__ float sAtot[4];

    const int eq = tid & 31;           // e-quad (cols 4eq..4eq+3)
    const int js = tid >> 5;           // 0..15 (j-split; doubles as kh in GEMVs)

    // early independent loads: H1a fragments for our 4 rows
    const f4* __restrict__ Ha4 = (const f4*)(H1a + (size_t)row0 * DD);
    const f4 pa0 = Ha4[0 * 32 + eq];
    const f4 pa1 = Ha4[1 * 32 + eq];
    const f4 pa2 = Ha4[2 * 32 + eq];
    const f4 pa3 = Ha4[3 * 32 + eq];

    // stage coords (768 floats = 192 float4)
    const float* __restrict__ cb = coords + (size_t)b * NN * 3;
    if (tid < 192) ((f4*)cS)[tid] = ((const f4*)cb)[tid];
    __syncthreads();

    // A: thread (rA = tid>>8 in {0,1}, j = tid&255) computes rows rA, rA+2
    {
        const int j = tid & 255, rA = tid >> 8;
        const float cjx = cS[j * 3], cjy = cS[j * 3 + 1], cjz = cS[j * 3 + 2];
        float* __restrict__ AsF = (float*)As4;
        {
            const int ii = i0 + rA;
            const float dx = cjx - cS[ii * 3], dy = cjy - cS[ii * 3 + 1], dz = cjz - cS[ii * 3 + 2];
            AsF[j * 4 + rA] = __expf(-0.5f * (dx * dx + dy * dy + dz * dz));
        }
        {
            const int ii = i0 + rA + 2;
            const float dx = cjx - cS[ii * 3], dy = cjy - cS[ii * 3 + 1], dz = cjz - cS[ii * 3 + 2];
            AsF[j * 4 + rA + 2] = __expf(-0.5f * (dx * dx + dy * dy + dz * dz));
        }
    }
    __syncthreads();

    // ---- Phase J: acc[r] = sum_{j in my 16} A[r][j]*relu(pa[r]+h1b[j])
    const f4* __restrict__ Hb4 = (const f4*)(H1b + (size_t)b * NN * DD);
    f4 v[16];
    #pragma unroll
    for (int t = 0; t < 16; ++t) v[t] = Hb4[(size_t)(js * 16 + t) * 32 + eq];

    f4 a0 = ZERO4, a1 = ZERO4, a2 = ZERO4, a3 = ZERO4, sA4 = ZERO4;
    #pragma unroll
    for (int t = 0; t < 16; ++t) {
        const f4 a = As4[js * 16 + t];   // near-uniform b128 (2 addrs/wave)
        sA4.x += a.x; sA4.y += a.y; sA4.z += a.z; sA4.w += a.w;
        FMA4R(a0, a.x, pa0, v[t]);
        FMA4R(a1, a.y, pa1, v[t]);
        FMA4R(a2, a.z, pa2, v[t]);
        FMA4R(a3, a.w, pa3, v[t]);
    }
    red[js * 128 + 0 * 32 + eq] = a0;
    red[js * 128 + 1 * 32 + eq] = a1;
    red[js * 128 + 2 * 32 + eq] = a2;
    red[js * 128 + 3 * 32 + eq] = a3;
    if (eq == 0) sAs4[js] = sA4;
    __syncthreads();

    // ---- Phase R: reduce 16 partials -> R_T ; sAtot
    const float* __restrict__ redF = (const float*)red;
    {
        const int r = tid >> 7, e = tid & 127;
        float s = 0.f;
        #pragma unroll
        for (int q = 0; q < 16; ++q) s += redF[q * 512 + r * 128 + e];
        ((float*)R_T)[e * 4 + r] = s;
    }
    if (tid < 4) {
        const float* __restrict__ sF = (const float*)sAs4;
        float s = 0.f;
        #pragma unroll
        for (int q = 0; q < 16; ++q) s += sF[q * 4 + tid];
        sAtot[tid] = s;
    }
    __syncthreads();

    // ---- Phase G1: agg-partials = R @ mW2 (4 rows x 4 cols x 8 k per thread)
    const int cq = eq, kh = js;
    const f4* __restrict__ W2g = (const f4*)mW2;
    {
        f4 wv[8];
        #pragma unroll
        for (int t = 0; t < 8; ++t) wv[t] = W2g[(size_t)(kh * 8 + t) * 32 + cq];
        f4 g0 = ZERO4, g1 = ZERO4, g2 = ZERO4, g3 = ZERO4;
        #pragma unroll
        for (int t = 0; t < 8; ++t) {
            const f4 rv = R_T[kh * 8 + t];
            FMA4(g0, rv.x, wv[t]);
            FMA4(g1, rv.y, wv[t]);
            FMA4(g2, rv.z, wv[t]);
            FMA4(g3, rv.w, wv[t]);
        }
        red[kh * 128 + 0 * 32 + cq] = g0;
        red[kh * 128 + 1 * 32 + cq] = g1;
        red[kh * 128 + 2 * 32 + cq] = g2;
        red[kh * 128 + 3 * 32 + cq] = g3;
    }
    __syncthreads();

    // ---- Phase U: reduce + assemble upd_in (agg + sA*mb2; coords tail)
    {
        const int r = tid >> 7, e = tid & 127;
        const float m2 = mb2[e];
        float s = sAtot[r] * m2;
        #pragma unroll
        for (int q = 0; q < 16; ++q) s += redF[q * 512 + r * 128 + e];
        ((float*)U_T)[e * 4 + r] = s;
    }
    if (tid < 12) {
        const int r = tid & 3, c = tid >> 2;
        ((float*)U_T)[(DD + c) * 4 + r] = cS[(i0 + r) * 3 + c];
    }
    __syncthreads();

    // ---- Phase G2: hid-partials = upd_in @ uW1 (131 k-rows; kh==15 takes tail)
    const f4* __restrict__ U1g = (const f4*)uW1;
    {
        f4 wv[8];
        #pragma unroll
        for (int t = 0; t < 8; ++t) wv[t] = U1g[(size_t)(kh * 8 + t) * 32 + cq];
        f4 g0 = ZERO4, g1 = ZERO4, g2 = ZERO4, g3 = ZERO4;
        #pragma unroll
        for (int t = 0; t < 8; ++t) {
            const f4 uv = U_T[kh * 8 + t];
            FMA4(g0, uv.x, wv[t]);
            FMA4(g1, uv.y, wv[t]);
            FMA4(g2, uv.z, wv[t]);
            FMA4(g3, uv.w, wv[t]);
        }
        if (kh == 15) {
            #pragma unroll
            for (int t = 0; t < 3; ++t) {
                const f4 wt = U1g[(size_t)(DD + t) * 32 + cq];
                const f4 uv = U_T[DD + t];
                FMA4(g0, uv.x, wt);
                FMA4(g1, uv.y, wt);
                FMA4(g2, uv.z, wt);
                FMA4(g3, uv.w, wt);
            }
        }
        red[kh * 128 + 0 * 32 + cq] = g0;
        red[kh * 128 + 1 * 32 + cq] = g1;
        red[kh * 128 + 2 * 32 + cq] = g2;
        red[kh * 128 + 3 * 32 + cq] = g3;
    }
    __syncthreads();

    // ---- Phase H: reduce + relu -> h_T
    {
        const int r = tid >> 7, e = tid & 127;
        float s = ub1[e];
        #pragma unroll
        for (int q = 0; q < 16; ++q) s += redF[q * 512 + r * 128 + e];
        ((float*)h_T)[e * 4 + r] = fmaxf(s, 0.f);
    }
    __syncthreads();

    // ---- Phase G3: delta-partials = hid @ uW2
    const f4* __restrict__ U2g = (const f4*)uW2;
    {
        f4 wv[8];
        #pragma unroll
        for (int t = 0; t < 8; ++t) wv[t] = U2g[(size_t)(kh * 8 + t) * 32 + cq];
        f4 g0 = ZERO4, g1 = ZERO4, g2 = ZERO4, g3 = ZERO4;
        #pragma unroll
        for (int t = 0; t < 8; ++t) {
            const f4 hv = h_T[kh * 8 + t];
            FMA4(g0, hv.x, wv[t]);
            FMA4(g1, hv.y, wv[t]);
            FMA4(g2, hv.z, wv[t]);
            FMA4(g3, hv.w, wv[t]);
        }
        red[kh * 128 + 0 * 32 + cq] = g0;
        red[kh * 128 + 1 * 32 + cq] = g1;
        red[kh * 128 + 2 * 32 + cq] = g2;
        red[kh * 128 + 3 * 32 + cq] = g3;
    }
    __syncthreads();

    // ---- Final: reduce + residual
    {
        const int r = tid >> 7, e = tid & 127;
        float s = ub2[e];
        #pragma unroll
        for (int q = 0; q < 16; ++q) s += redF[q * 512 + r * 128 + e];
        out[(size_t)(row0 + r) * DD + e] = emb[(size_t)(row0 + r) * DD + e] + s;
    }
}

extern "C" void kernel_launch(void* const* d_in, const int* in_sizes, int n_in,
                              void* d_out, int out_size, void* d_ws, size_t ws_size,
                              hipStream_t stream) {
    const float* emb    = (const float*)d_in[0];
    const float* coords = (const float*)d_in[1];
    const float* mW1    = (const float*)d_in[2];
    const float* mb1    = (const float*)d_in[3];
    const float* mW2    = (const float*)d_in[4];
    const float* mb2    = (const float*)d_in[5];
    const float* uW1    = (const float*)d_in[6];
    const float* ub1    = (const float*)d_in[7];
    const float* uW2    = (const float*)d_in[8];
    const float* ub2    = (const float*)d_in[9];
    float* out = (float*)d_out;

    float* H1a = (float*)d_ws;
    float* H1b = H1a + 4 * NN * DD;

    h1_kernel<<<dim3(256), dim3(512), 0, stream>>>(emb, mW1, mb1, H1a, H1b);
    gnn_kernel<<<dim3(256), dim3(512), 0, stream>>>(
        emb, coords, mW2, mb2, uW1, ub1, uW2, ub2, H1a, H1b, out);
}